// Round 2
// baseline (101.276 us; speedup 1.0000x reference)
//
#include <hip/hip_runtime.h>

#define IMG 8
#define LH 150
#define LQ 10
#define KITER 10   // 9 scan steps + final conv
#define ROW (IMG * IMG + 2)   // 66 floats per batch row

// Packed fp32 pair: item0 in .x, item1 in .y -> v_pk_* (full-rate on CDNA).
typedef float f32x2 __attribute__((ext_vector_type(2)));

// ds_bpermute with precomputed BYTE address. Full-wave convergence required.
__device__ __forceinline__ float bperm(int byte_addr, float v) {
    return __builtin_bit_cast(float,
        __builtin_amdgcn_ds_bpermute(byte_addr, __builtin_bit_cast(int, v)));
}

// Force a wave-uniform value into an SGPR.
__device__ __forceinline__ float rfl(float v) {
    return __builtin_bit_cast(float,
        __builtin_amdgcn_readfirstlane(__builtin_bit_cast(int, v)));
}

// DPP lane shift within 16-lane rows. 0x111 = row_shr:1 (lane i <- i-1),
// 0x101 = row_shl:1 (lane i <- i+1). Bound lanes -> 0.0 (bound_ctrl);
// cross-grid-row lanes (x==0 / x==7) produce garbage that gets value-masked.
template <int CTRL>
__device__ __forceinline__ float dppf(float v) {
    return __builtin_bit_cast(float,
        __builtin_amdgcn_update_dpp(0, __builtin_bit_cast(int, v),
                                    CTRL, 0xF, 0xF, true));
}
#define DPP_SHR1 0x111
#define DPP_SHL1 0x101

__device__ __forceinline__ f32x2 fma2(f32x2 a, f32x2 b, f32x2 c) {
#if __has_builtin(__builtin_elementwise_fma)
    return __builtin_elementwise_fma(a, b, c);
#else
    return a * b + c;
#endif
}
__device__ __forceinline__ f32x2 max2(f32x2 a, f32x2 b) {
#if __has_builtin(__builtin_elementwise_max)
    return __builtin_elementwise_max(a, b);   // v_pk_max_f32
#else
    f32x2 r; r.x = fmaxf(a.x, b.x); r.y = fmaxf(a.y, b.y); return r;
#endif
}
// Broadcast a scalar (SGPR for uniform s) into both pk halves.
__device__ __forceinline__ f32x2 set2(float s) { f32x2 r; r.x = s; r.y = s; return r; }
// Packed multiply by per-lane scalar mask (compiler dedups halves via op_sel).
__device__ __forceinline__ f32x2 mulm(f32x2 v, float m) {
    f32x2 r; r.x = v.x * m; r.y = v.y * m; return r;
}

// 3x3 neighbor gather for a packed pair: 4 ds_bpermute (vertical, lane+-8)
// + 12 DPP movs (horizontal, lane+-1) + center free.
__device__ __forceinline__ void gather9(f32x2 vn[9], f32x2 v, int aU, int aD) {
    f32x2 vU, vD;
    vU.x = bperm(aU, v.x); vU.y = bperm(aU, v.y);
    vD.x = bperm(aD, v.x); vD.y = bperm(aD, v.y);
    vn[1] = vU; vn[4] = v; vn[7] = vD;
    vn[0].x = dppf<DPP_SHR1>(vU.x); vn[0].y = dppf<DPP_SHR1>(vU.y);
    vn[2].x = dppf<DPP_SHL1>(vU.x); vn[2].y = dppf<DPP_SHL1>(vU.y);
    vn[3].x = dppf<DPP_SHR1>(v.x);  vn[3].y = dppf<DPP_SHR1>(v.y);
    vn[5].x = dppf<DPP_SHL1>(v.x);  vn[5].y = dppf<DPP_SHL1>(v.y);
    vn[6].x = dppf<DPP_SHR1>(vD.x); vn[6].y = dppf<DPP_SHR1>(vD.y);
    vn[8].x = dppf<DPP_SHL1>(vD.x); vn[8].y = dppf<DPP_SHL1>(vD.y);
}

// ---------------------------------------------------------------------------
// Pre-kernel: collapse h/r convs (exact — no nonlinearity between h and r).
// ---------------------------------------------------------------------------
__global__ void weff_kernel(const float* __restrict__ Wh,
                            const float* __restrict__ bh,
                            const float* __restrict__ Wr,
                            float* __restrict__ ws) {
    const int wv = threadIdx.x >> 6;   // 0..9 (wave-uniform)
    const int lane = threadIdx.x & 63;
    float partial = 0.f;
    for (int c = lane; c < LH; c += 64) {
        const float wr = Wr[c];
        partial += wr * ((wv < 9) ? Wh[c * 9 + wv] : bh[c]);
    }
    #pragma unroll
    for (int off = 32; off > 0; off >>= 1)
        partial += __shfl_xor(partial, off);   // full wave active
    if (lane == 0) ws[wv] = partial;
}

// ---------------------------------------------------------------------------
// Main kernel. Round-9 change vs previous (which was latency-bound:
// VGPR=108 -> 4 waves/SIMD cap, measured occupancy 18.7%, VALUBusy 42%):
// the 90 scan weights move from per-lane-masked VGPRs to wave-uniform SGPRs
// (readfirstlane-pinned, preloaded AFTER init so they don't collide with
// init SGPR pressure, and NOT s_loaded inside the loop -> no lgkmcnt
// entanglement with ds_bpermute). The zero-pad mask moves onto the gathered
// VALUES: 8 v_pk_mul per step (tap 4 always valid). Exact: vn*m*w == vn*(w*m)
// for m in {0,1}. Frees ~90 VGPRs -> target <=72 live -> 6-8 waves/SIMD.
// ---------------------------------------------------------------------------
__global__ __launch_bounds__(256, 6) void vin_kernel(
    const float* __restrict__ S,
    const float* __restrict__ Wq,
    const float* __restrict__ w,
    const float* __restrict__ Wfc,
    const float* __restrict__ ws,
    float* __restrict__ out,
    int B) {
    const int wave = threadIdx.x >> 6;
    const int lane = threadIdx.x & 63;
    const long b0 = (long)(blockIdx.x * 4 + wave) * 2;   // items b0, b0+1
    if (b0 >= B) return;                                  // wave-uniform

    const int y = lane >> 3, x = lane & 7;

    // Zero-pad masks for the 9 taps; vertical-neighbor byte addresses.
    float msk[9];
    #pragma unroll
    for (int t = 0; t < 9; ++t) {
        const int ny = y + t / 3 - 1, nx = x + t % 3 - 1;
        msk[t] = (((unsigned)ny < 8u) && ((unsigned)nx < 8u)) ? 1.f : 0.f;
    }
    const int aU = ((y > 0) ? (lane - 8) : 0) << 2;
    const int aD = ((y < 7) ? (lane + 8) : 0) << 2;

    const float* S0 = S + b0 * ROW;
    f32x2 X; X.x = S0[lane]; X.y = S0[ROW + lane];
    const int sel0 = ((int)S0[IMG * IMG] * 8 + (int)S0[IMG * IMG + 1]) << 2;
    const int sel1 = ((int)S0[ROW + IMG * IMG] * 8 + (int)S0[ROW + IMG * IMG + 1]) << 2;

    // r = conv(X, Weff, pad=1) + beff   (packed pair)
    f32x2 r;
    {
        f32x2 xn[9]; gather9(xn, X, aU, aD);
        const float b = ws[9];
        r = set2(b);
        #pragma unroll
        for (int t = 0; t < 9; ++t) {
            const float wm = ws[t] * msk[t];
            r = fma2(xn[t], set2(wm), r);
        }
    }

    // qr[o] = conv(r, Wq, pad=1) — loop-invariant across the value iteration.
    f32x2 qr[LQ];
    {
        f32x2 rn[9]; gather9(rn, r, aU, aD);
        #pragma unroll
        for (int t = 0; t < 9; ++t) {
            const f32x2 a = mulm(rn[t], msk[t]);
            #pragma unroll
            for (int o = 0; o < LQ; ++o) {
                const float wq = Wq[o * 9 + t];      // wave-uniform (SGPR)
                qr[o] = (t == 0) ? (a * set2(wq)) : fma2(a, set2(wq), qr[o]);
            }
        }
    }

    // Wave-uniform scan weights pinned to SGPRs (loaded after init so init
    // SGPR lifetimes are over; never re-loaded inside the loop).
    float wu[LQ][9];
    #pragma unroll
    for (int o = 0; o < LQ; ++o)
        #pragma unroll
        for (int t = 0; t < 9; ++t)
            wu[o][t] = rfl(w[o * 9 + t]);

    // v = max over channels of qr (packed max tree)
    f32x2 v;
    {
        const f32x2 g0 = max2(max2(qr[0], qr[1]), qr[2]);
        const f32x2 g1 = max2(max2(qr[3], qr[4]), qr[5]);
        const f32x2 g2 = max2(max2(qr[6], qr[7]), qr[8]);
        v = max2(max2(g0, g1), max2(g2, qr[9]));
    }

    // 9 scan steps: gather (4 bperm + 12 dpp) -> 8 pk_mul mask -> 90 pk_fma
    // (SGPR weight broadcast) -> packed max tree.
    #pragma unroll
    for (int k = 0; k < KITER - 1; ++k) {
        f32x2 vn[9]; gather9(vn, v, aU, aD);
        #pragma unroll
        for (int t = 0; t < 9; ++t)
            if (t != 4) vn[t] = mulm(vn[t], msk[t]);
        f32x2 m;
        #pragma unroll
        for (int o = 0; o < LQ; ++o) {
            f32x2 acc = qr[o];
            #pragma unroll
            for (int t = 0; t < 9; ++t)
                acc = fma2(vn[t], set2(wu[o][t]), acc);
            m = (o == 0) ? acc : max2(m, acc);
        }
        v = m;
    }

    // Final conv fused with sel-lane broadcast and the Wfc dot (streamed).
    float oacc = 0.f;
    {
        f32x2 vn[9]; gather9(vn, v, aU, aD);
        #pragma unroll
        for (int t = 0; t < 9; ++t)
            if (t != 4) vn[t] = mulm(vn[t], msk[t]);
        const int row = lane & 7;
        #pragma unroll
        for (int o = 0; o < LQ; ++o) {
            f32x2 acc = qr[o];
            #pragma unroll
            for (int t = 0; t < 9; ++t)
                acc = fma2(vn[t], set2(wu[o][t]), acc);
            const float q0 = bperm(sel0, acc.x);     // full convergence
            const float q1 = bperm(sel1, acc.y);
            oacc = fmaf((lane < 8) ? q0 : q1, Wfc[row * LQ + o], oacc);
        }
    }
    // Lanes 0..7 emit item b0's logits, lanes 8..15 item b0+1's.
    if (lane < 16) out[b0 * 8 + lane] = oacc;
}

extern "C" void kernel_launch(void* const* d_in, const int* in_sizes, int n_in,
                              void* d_out, int out_size, void* d_ws, size_t ws_size,
                              hipStream_t stream) {
    const float* S   = (const float*)d_in[0];
    const float* Wh  = (const float*)d_in[1];
    const float* bh  = (const float*)d_in[2];
    const float* Wr  = (const float*)d_in[3];
    const float* Wq  = (const float*)d_in[4];
    const float* w   = (const float*)d_in[5];
    const float* Wfc = (const float*)d_in[6];
    float* out = (float*)d_out;
    float* ws  = (float*)d_ws;

    const int B = in_sizes[0] / ROW;

    weff_kernel<<<1, 640, 0, stream>>>(Wh, bh, Wr, ws);

    // 4 waves/block, 2 items/wave => 8 items per block.
    const int grid = (B + 7) / 8;
    vin_kernel<<<grid, 256, 0, stream>>>(S, Wq, w, Wfc, ws, out, B);
}

// Round 3
// 99.434 us; speedup vs baseline: 1.0185x; 1.0185x over previous
//
#include <hip/hip_runtime.h>

#define IMG 8
#define LH 150
#define LQ 10
#define KITER 10   // 9 scan steps + final conv
#define ROW (IMG * IMG + 2)   // 66 floats per batch row

// ds_bpermute with precomputed BYTE address. Full-wave convergence required.
// Only used ONCE (sel-lane broadcast at the end) — the hot loop is DS-free.
__device__ __forceinline__ float bperm(int byte_addr, float v) {
    return __builtin_bit_cast(float,
        __builtin_amdgcn_ds_bpermute(byte_addr, __builtin_bit_cast(int, v)));
}

// DPP lane shift within 16-lane rows, bound_ctrl=1 (out-of-bounds -> 0.0).
template <int CTRL>
__device__ __forceinline__ float dppf(float v) {
    return __builtin_bit_cast(float,
        __builtin_amdgcn_update_dpp(0, __builtin_bit_cast(int, v),
                                    CTRL, 0xF, 0xF, true));
}
#define DPP_SHR1 0x111   // lane i <- i-1  (x-1)
#define DPP_SHL1 0x101   // lane i <- i+1  (x+1)
#define DPP_SHR8 0x118   // lane i <- i-8  (y-1 across half boundary; half0 -> 0 = top pad)
#define DPP_SHL8 0x108   // lane i <- i+8  (y+1 across half boundary; half1 -> 0 = bottom pad)

// ---------------------------------------------------------------------------
// Build the 18 tap-source rows for a 3x3 conv from the 4 per-lane y-registers.
// C[j] = row values for global source row (half*4 + j - 1), j=0..5:
//   C[0] = y-1 of yr0 (cross-half via row_shr:8; hardware 0 for half0 = top pad)
//   C[1..4] = v[0..3]
//   C[5] = y+1 of yr3 (cross-half via row_shl:8; hardware 0 for half1 = bottom pad)
// L/R = x-1 / x+1 shifted copies, zero-pad masked at the x=0/x=7 item edges.
// All VALU, no DS.
// ---------------------------------------------------------------------------
__device__ __forceinline__ void taps6(const float v[4], float C[6],
                                      float L[6], float R6[6],
                                      float mskL, float mskR) {
    C[0] = dppf<DPP_SHR8>(v[3]);
    C[1] = v[0]; C[2] = v[1]; C[3] = v[2]; C[4] = v[3];
    C[5] = dppf<DPP_SHL8>(v[0]);
    #pragma unroll
    for (int j = 0; j < 6; ++j) {
        L[j]  = mskL * dppf<DPP_SHR1>(C[j]);
        R6[j] = mskR * dppf<DPP_SHL1>(C[j]);
    }
}

// ---------------------------------------------------------------------------
// Pre-kernel: collapse h/r convs (exact — no nonlinearity between h and r).
// ---------------------------------------------------------------------------
__global__ void weff_kernel(const float* __restrict__ Wh,
                            const float* __restrict__ bh,
                            const float* __restrict__ Wr,
                            float* __restrict__ ws) {
    const int wv = threadIdx.x >> 6;   // 0..9 (wave-uniform)
    const int lane = threadIdx.x & 63;
    float partial = 0.f;
    for (int c = lane; c < LH; c += 64) {
        const float wr = Wr[c];
        partial += wr * ((wv < 9) ? Wh[c * 9 + wv] : bh[c]);
    }
    #pragma unroll
    for (int off = 32; off > 0; off >>= 1)
        partial += __shfl_xor(partial, off);   // full wave active
    if (lane == 0) ws[wv] = partial;
}

// ---------------------------------------------------------------------------
// Main kernel, round-10 layout change. Previous rounds were bound by the
// per-step ds_bpermute latency chain (VALUBusy 70%, 30% stall) and pk_fma
// turned out to be half-rate (no FLOP gain). New decomposition:
//   lane = item*16 + half*8 + x ; y = half*4 + yr with yr in 4 REGISTERS.
// -> vertical taps are register accesses; vertical zero-padding comes free
//    from DPP row_shr:8 / row_shl:8 bound_ctrl zeros; horizontal taps are
//    1-lane DPP + {0,1} value masks. The 10-step scan has ZERO DS ops.
// Scalar v_fma throughout (FP32 pipe = 32 MAC/cyc/SIMD regardless of
// packing). Scan weights indexed uniformly -> s_loads, hoisted out of the
// (#pragma unroll 1) k-loop; body ~410 instr fits L1I.
// Arithmetic order per output is identical to the verified R2 kernel
// (tap-ascending fma chain from the same base), so results are bit-identical.
// ---------------------------------------------------------------------------
__global__ __launch_bounds__(256, 4) void vin_kernel(
    const float* __restrict__ S,
    const float* __restrict__ Wq,
    const float* __restrict__ w,
    const float* __restrict__ Wfc,
    const float* __restrict__ ws,
    float* __restrict__ out,
    int B) {
    const int wave = threadIdx.x >> 6;
    const int lane = threadIdx.x & 63;
    const long b0 = (long)(blockIdx.x * 4 + wave) * 4;   // items b0..b0+3
    if (b0 >= B) return;                                  // wave-uniform

    const int grp  = lane >> 4;        // item within wave (0..3)
    const int half = (lane >> 3) & 1;  // y half (0: y=0..3, 1: y=4..7)
    const int x    = lane & 7;
    const float mskL = (x > 0) ? 1.f : 0.f;
    const float mskR = (x < 7) ? 1.f : 0.f;

    const long b = b0 + grp;
    const float* Sb = S + b * ROW;

    // 4 grid rows per lane (global y = half*4 + yr), plus sel coords.
    float v[4];
    #pragma unroll
    for (int yr = 0; yr < 4; ++yr)
        v[yr] = Sb[(half * 4 + yr) * 8 + x];
    const int s1i = (int)Sb[IMG * IMG];
    const int s2i = (int)Sb[IMG * IMG + 1];
    // wave lane holding the selected pixel of this item
    const int selAddr = ((grp << 4) + ((s1i & 4) << 1) + s2i) << 2;

    // --- r = conv(X, Weff, pad=1) + beff  (in place: v becomes r)
    {
        float C[6], L[6], R6[6];
        taps6(v, C, L, R6, mskL, mskR);
        const float bias = ws[9];
        #pragma unroll
        for (int yr = 0; yr < 4; ++yr) {
            float a = bias;
            #pragma unroll
            for (int ky = 0; ky < 3; ++ky) {
                const int j = yr + ky;
                a = fmaf(L[j],  ws[ky * 3 + 0], a);
                a = fmaf(C[j],  ws[ky * 3 + 1], a);
                a = fmaf(R6[j], ws[ky * 3 + 2], a);
            }
            v[yr] = a;
        }
    }

    // --- qr[o] = conv(r, Wq, pad=1) — loop-invariant across the scan.
    float qr[LQ][4];
    {
        float C[6], L[6], R6[6];
        taps6(v, C, L, R6, mskL, mskR);
        #pragma unroll
        for (int o = 0; o < LQ; ++o) {
            #pragma unroll
            for (int yr = 0; yr < 4; ++yr) {
                float a = L[yr] * Wq[o * 9 + 0];
                a = fmaf(C[yr],      Wq[o * 9 + 1], a);
                a = fmaf(R6[yr],     Wq[o * 9 + 2], a);
                a = fmaf(L[yr + 1],  Wq[o * 9 + 3], a);
                a = fmaf(C[yr + 1],  Wq[o * 9 + 4], a);
                a = fmaf(R6[yr + 1], Wq[o * 9 + 5], a);
                a = fmaf(L[yr + 2],  Wq[o * 9 + 6], a);
                a = fmaf(C[yr + 2],  Wq[o * 9 + 7], a);
                a = fmaf(R6[yr + 2], Wq[o * 9 + 8], a);
                qr[o][yr] = a;
            }
        }
    }

    // v = max over channels of qr (same tree shape as the verified max10)
    #pragma unroll
    for (int yr = 0; yr < 4; ++yr) {
        const float g0 = fmaxf(fmaxf(qr[0][yr], qr[1][yr]), qr[2][yr]);
        const float g1 = fmaxf(fmaxf(qr[3][yr], qr[4][yr]), qr[5][yr]);
        const float g2 = fmaxf(fmaxf(qr[6][yr], qr[7][yr]), qr[8][yr]);
        v[yr] = fmaxf(fmaxf(g0, g1), fmaxf(g2, qr[9][yr]));
    }

    // --- 9 scan steps. NOT unrolled: keeps body in L1I and the 90 scan
    // weights hoisted into SGPRs once (uniform s_loads, loop-invariant).
    #pragma unroll 1
    for (int k = 0; k < KITER - 1; ++k) {
        float C[6], L[6], R6[6];
        taps6(v, C, L, R6, mskL, mskR);
        float q[LQ][4];
        #pragma unroll
        for (int o = 0; o < LQ; ++o) {
            #pragma unroll
            for (int yr = 0; yr < 4; ++yr) {
                float a = qr[o][yr];
                a = fmaf(L[yr],      w[o * 9 + 0], a);
                a = fmaf(C[yr],      w[o * 9 + 1], a);
                a = fmaf(R6[yr],     w[o * 9 + 2], a);
                a = fmaf(L[yr + 1],  w[o * 9 + 3], a);
                a = fmaf(C[yr + 1],  w[o * 9 + 4], a);
                a = fmaf(R6[yr + 1], w[o * 9 + 5], a);
                a = fmaf(L[yr + 2],  w[o * 9 + 6], a);
                a = fmaf(C[yr + 2],  w[o * 9 + 7], a);
                a = fmaf(R6[yr + 2], w[o * 9 + 8], a);
                q[o][yr] = a;
            }
        }
        #pragma unroll
        for (int yr = 0; yr < 4; ++yr) {
            const float g0 = fmaxf(fmaxf(q[0][yr], q[1][yr]), q[2][yr]);
            const float g1 = fmaxf(fmaxf(q[3][yr], q[4][yr]), q[5][yr]);
            const float g2 = fmaxf(fmaxf(q[6][yr], q[7][yr]), q[8][yr]);
            v[yr] = fmaxf(fmaxf(g0, g1), fmaxf(g2, q[9][yr]));
        }
    }

    // --- Final conv fused with sel extraction + Wfc dot.
    // e[yr] selects the register row matching s1 (zero on the wrong half).
    float e[4];
    #pragma unroll
    for (int yr = 0; yr < 4; ++yr)
        e[yr] = (s1i == half * 4 + yr) ? 1.f : 0.f;

    const int row = lane & 7;
    float osum = 0.f;
    {
        float C[6], L[6], R6[6];
        taps6(v, C, L, R6, mskL, mskR);
        #pragma unroll
        for (int o = 0; o < LQ; ++o) {
            float t;
            {
                float ayr[4];
                #pragma unroll
                for (int yr = 0; yr < 4; ++yr) {
                    float a = qr[o][yr];
                    a = fmaf(L[yr],      w[o * 9 + 0], a);
                    a = fmaf(C[yr],      w[o * 9 + 1], a);
                    a = fmaf(R6[yr],     w[o * 9 + 2], a);
                    a = fmaf(L[yr + 1],  w[o * 9 + 3], a);
                    a = fmaf(C[yr + 1],  w[o * 9 + 4], a);
                    a = fmaf(R6[yr + 1], w[o * 9 + 5], a);
                    a = fmaf(L[yr + 2],  w[o * 9 + 6], a);
                    a = fmaf(C[yr + 2],  w[o * 9 + 7], a);
                    a = fmaf(R6[yr + 2], w[o * 9 + 8], a);
                    ayr[yr] = a;
                }
                t = ayr[0] * e[0];
                t = fmaf(ayr[1], e[1], t);
                t = fmaf(ayr[2], e[2], t);
                t = fmaf(ayr[3], e[3], t);
            }
            const float qs = bperm(selAddr, t);   // full convergence
            osum = fmaf(qs, Wfc[row * LQ + o], osum);
        }
    }
    // lanes 0..7 of each 16-lane group emit their item's 8 logits
    if ((lane & 15) < 8) out[b * 8 + row] = osum;
}

extern "C" void kernel_launch(void* const* d_in, const int* in_sizes, int n_in,
                              void* d_out, int out_size, void* d_ws, size_t ws_size,
                              hipStream_t stream) {
    const float* S   = (const float*)d_in[0];
    const float* Wh  = (const float*)d_in[1];
    const float* bh  = (const float*)d_in[2];
    const float* Wr  = (const float*)d_in[3];
    const float* Wq  = (const float*)d_in[4];
    const float* w   = (const float*)d_in[5];
    const float* Wfc = (const float*)d_in[6];
    float* out = (float*)d_out;
    float* ws  = (float*)d_ws;

    const int B = in_sizes[0] / ROW;

    weff_kernel<<<1, 640, 0, stream>>>(Wh, bh, Wr, ws);

    // 4 waves/block, 4 items/wave => 16 items per block.
    const int grid = (B + 15) / 16;
    vin_kernel<<<grid, 256, 0, stream>>>(S, Wq, w, Wfc, ws, out, B);
}

// Round 4
// 98.546 us; speedup vs baseline: 1.0277x; 1.0090x over previous
//
#include <hip/hip_runtime.h>

#define IMG 8
#define LH 150
#define LQ 10
#define KITER 10   // 9 scan steps + final conv
#define ROW (IMG * IMG + 2)   // 66 floats per batch row

// ds_bpermute with precomputed BYTE address. Full-wave convergence required.
// Only used ONCE (sel-lane broadcast at the end) — the hot loop is DS-free.
__device__ __forceinline__ float bperm(int byte_addr, float v) {
    return __builtin_bit_cast(float,
        __builtin_amdgcn_ds_bpermute(byte_addr, __builtin_bit_cast(int, v)));
}

// Force a wave-uniform value into an SGPR (weight pinning: keeps the scan
// loop free of s_loads and lgkmcnt waits).
__device__ __forceinline__ float rfl(float v) {
    return __builtin_bit_cast(float,
        __builtin_amdgcn_readfirstlane(__builtin_bit_cast(int, v)));
}

// DPP lane shift within 16-lane rows, bound_ctrl=1 (out-of-bounds -> 0.0).
template <int CTRL>
__device__ __forceinline__ float dppf(float v) {
    return __builtin_bit_cast(float,
        __builtin_amdgcn_update_dpp(0, __builtin_bit_cast(int, v),
                                    CTRL, 0xF, 0xF, true));
}
#define DPP_SHR1 0x111   // lane i <- i-1  (x-1)
#define DPP_SHL1 0x101   // lane i <- i+1  (x+1)
#define DPP_SHR8 0x118   // lane i <- i-8  (y-1 cross-half; half0 -> 0 = top pad)
#define DPP_SHL8 0x108   // lane i <- i+8  (y+1 cross-half; half1 -> 0 = bottom pad)

// ---------------------------------------------------------------------------
// Build the 18 tap-source rows for a 3x3 conv from the 4 per-lane y-registers.
// Lane = item*16 + half*8 + x; per-lane rows y = half*4 + {0..3}.
//   C[0] = y-1 of v[3] from the other half (row_shr:8; bound 0 = top pad)
//   C[1..4] = v[0..3]
//   C[5] = y+1 of v[0] from the other half (row_shl:8; bound 0 = bottom pad)
// L/R = x-1/x+1 via 1-lane DPP; mskL/mskR zero the x-edge cross-contamination
// (lane 8 on SHR1 / lane 7 on SHL1 within each 16-lane item group).
// All VALU, no DS.
// ---------------------------------------------------------------------------
__device__ __forceinline__ void taps6(const float v[4], float C[6],
                                      float L[6], float R6[6],
                                      float mskL, float mskR) {
    C[0] = dppf<DPP_SHR8>(v[3]);
    C[1] = v[0]; C[2] = v[1]; C[3] = v[2]; C[4] = v[3];
    C[5] = dppf<DPP_SHL8>(v[0]);
    #pragma unroll
    for (int j = 0; j < 6; ++j) {
        L[j]  = mskL * dppf<DPP_SHR1>(C[j]);
        R6[j] = mskR * dppf<DPP_SHL1>(C[j]);
    }
}

// ---------------------------------------------------------------------------
// Pre-kernel: collapse h/r convs (exact — no nonlinearity between h and r).
// ---------------------------------------------------------------------------
__global__ void weff_kernel(const float* __restrict__ Wh,
                            const float* __restrict__ bh,
                            const float* __restrict__ Wr,
                            float* __restrict__ ws) {
    const int wv = threadIdx.x >> 6;   // 0..9 (wave-uniform)
    const int lane = threadIdx.x & 63;
    float partial = 0.f;
    for (int c = lane; c < LH; c += 64) {
        const float wr = Wr[c];
        partial += wr * ((wv < 9) ? Wh[c * 9 + wv] : bh[c]);
    }
    #pragma unroll
    for (int off = 32; off > 0; off >>= 1)
        partial += __shfl_xor(partial, off);   // full wave active
    if (lane == 0) ws[wv] = partial;
}

// ---------------------------------------------------------------------------
// Main kernel. Round-11 changes vs R3 (<40 us, est. ~50% stall vs the
// ~18 us VALU-issue floor):
//  (a) 90 scan weights pinned to SGPRs via readfirstlane BEFORE the k-loop
//      -> loop body has ZERO memory ops (R3 read w[] in-loop; if LICM kept
//      s_loads in the loop, each iter paid lgkmcnt waits on the fma path).
//  (b) running channel-max (m[yr] = fmax(m[yr], a)) instead of q[10][4]
//      -> ~36 fewer live VGPRs (exact: set-max is order-invariant).
//  (c) #pragma unroll 3 -> scheduler can overlap step k's dependent
//      max-chain tail with step k+1's DPP/fma stream.
// ---------------------------------------------------------------------------
__global__ __launch_bounds__(256, 4) void vin_kernel(
    const float* __restrict__ S,
    const float* __restrict__ Wq,
    const float* __restrict__ w,
    const float* __restrict__ Wfc,
    const float* __restrict__ ws,
    float* __restrict__ out,
    int B) {
    const int wave = threadIdx.x >> 6;
    const int lane = threadIdx.x & 63;
    const long b0 = (long)(blockIdx.x * 4 + wave) * 4;   // items b0..b0+3
    if (b0 >= B) return;                                  // wave-uniform

    const int grp  = lane >> 4;        // item within wave (0..3)
    const int half = (lane >> 3) & 1;  // y half (0: y=0..3, 1: y=4..7)
    const int x    = lane & 7;
    const float mskL = (x > 0) ? 1.f : 0.f;
    const float mskR = (x < 7) ? 1.f : 0.f;

    const long b = b0 + grp;
    const float* Sb = S + b * ROW;

    // 4 grid rows per lane (global y = half*4 + yr), plus sel coords.
    float v[4];
    #pragma unroll
    for (int yr = 0; yr < 4; ++yr)
        v[yr] = Sb[(half * 4 + yr) * 8 + x];
    const int s1i = (int)Sb[IMG * IMG];
    const int s2i = (int)Sb[IMG * IMG + 1];
    // wave lane holding the selected pixel of this item
    const int selAddr = ((grp << 4) + ((s1i & 4) << 1) + s2i) << 2;

    // --- r = conv(X, Weff, pad=1) + beff  (in place: v becomes r)
    {
        float C[6], L[6], R6[6];
        taps6(v, C, L, R6, mskL, mskR);
        const float bias = ws[9];
        #pragma unroll
        for (int yr = 0; yr < 4; ++yr) {
            float a = bias;
            #pragma unroll
            for (int ky = 0; ky < 3; ++ky) {
                const int j = yr + ky;
                a = fmaf(L[j],  ws[ky * 3 + 0], a);
                a = fmaf(C[j],  ws[ky * 3 + 1], a);
                a = fmaf(R6[j], ws[ky * 3 + 2], a);
            }
            v[yr] = a;
        }
    }

    // --- qr[o] = conv(r, Wq, pad=1) — loop-invariant across the scan.
    float qr[LQ][4];
    {
        float C[6], L[6], R6[6];
        taps6(v, C, L, R6, mskL, mskR);
        #pragma unroll
        for (int o = 0; o < LQ; ++o) {
            #pragma unroll
            for (int yr = 0; yr < 4; ++yr) {
                float a = L[yr] * Wq[o * 9 + 0];
                a = fmaf(C[yr],      Wq[o * 9 + 1], a);
                a = fmaf(R6[yr],     Wq[o * 9 + 2], a);
                a = fmaf(L[yr + 1],  Wq[o * 9 + 3], a);
                a = fmaf(C[yr + 1],  Wq[o * 9 + 4], a);
                a = fmaf(R6[yr + 1], Wq[o * 9 + 5], a);
                a = fmaf(L[yr + 2],  Wq[o * 9 + 6], a);
                a = fmaf(C[yr + 2],  Wq[o * 9 + 7], a);
                a = fmaf(R6[yr + 2], Wq[o * 9 + 8], a);
                qr[o][yr] = a;
            }
        }
    }

    // Pin the 90 scan weights to SGPRs (one-time; loop body then has NO
    // memory operations at all).
    float wu[LQ][9];
    #pragma unroll
    for (int o = 0; o < LQ; ++o)
        #pragma unroll
        for (int t = 0; t < 9; ++t)
            wu[o][t] = rfl(w[o * 9 + t]);

    // v = max over channels of qr
    #pragma unroll
    for (int yr = 0; yr < 4; ++yr) {
        const float g0 = fmaxf(fmaxf(qr[0][yr], qr[1][yr]), qr[2][yr]);
        const float g1 = fmaxf(fmaxf(qr[3][yr], qr[4][yr]), qr[5][yr]);
        const float g2 = fmaxf(fmaxf(qr[6][yr], qr[7][yr]), qr[8][yr]);
        v[yr] = fmaxf(fmaxf(g0, g1), fmaxf(g2, qr[9][yr]));
    }

    // --- 9 scan steps: pure VALU (dpp + fma + max), zero memory ops.
    #pragma unroll 3
    for (int k = 0; k < KITER - 1; ++k) {
        float C[6], L[6], R6[6];
        taps6(v, C, L, R6, mskL, mskR);
        float m[4];
        #pragma unroll
        for (int o = 0; o < LQ; ++o) {
            #pragma unroll
            for (int yr = 0; yr < 4; ++yr) {
                float a = qr[o][yr];
                a = fmaf(L[yr],      wu[o][0], a);
                a = fmaf(C[yr],      wu[o][1], a);
                a = fmaf(R6[yr],     wu[o][2], a);
                a = fmaf(L[yr + 1],  wu[o][3], a);
                a = fmaf(C[yr + 1],  wu[o][4], a);
                a = fmaf(R6[yr + 1], wu[o][5], a);
                a = fmaf(L[yr + 2],  wu[o][6], a);
                a = fmaf(C[yr + 2],  wu[o][7], a);
                a = fmaf(R6[yr + 2], wu[o][8], a);
                m[yr] = (o == 0) ? a : fmaxf(m[yr], a);
            }
        }
        #pragma unroll
        for (int yr = 0; yr < 4; ++yr) v[yr] = m[yr];
    }

    // --- Final conv fused with sel extraction + Wfc dot.
    float e[4];
    #pragma unroll
    for (int yr = 0; yr < 4; ++yr)
        e[yr] = (s1i == half * 4 + yr) ? 1.f : 0.f;

    const int row = lane & 7;
    float osum = 0.f;
    {
        float C[6], L[6], R6[6];
        taps6(v, C, L, R6, mskL, mskR);
        #pragma unroll
        for (int o = 0; o < LQ; ++o) {
            float t;
            {
                float ayr[4];
                #pragma unroll
                for (int yr = 0; yr < 4; ++yr) {
                    float a = qr[o][yr];
                    a = fmaf(L[yr],      wu[o][0], a);
                    a = fmaf(C[yr],      wu[o][1], a);
                    a = fmaf(R6[yr],     wu[o][2], a);
                    a = fmaf(L[yr + 1],  wu[o][3], a);
                    a = fmaf(C[yr + 1],  wu[o][4], a);
                    a = fmaf(R6[yr + 1], wu[o][5], a);
                    a = fmaf(L[yr + 2],  wu[o][6], a);
                    a = fmaf(C[yr + 2],  wu[o][7], a);
                    a = fmaf(R6[yr + 2], wu[o][8], a);
                    ayr[yr] = a;
                }
                t = ayr[0] * e[0];
                t = fmaf(ayr[1], e[1], t);
                t = fmaf(ayr[2], e[2], t);
                t = fmaf(ayr[3], e[3], t);
            }
            const float qs = bperm(selAddr, t);   // full convergence
            osum = fmaf(qs, Wfc[row * LQ + o], osum);
        }
    }
    // lanes 0..7 of each 16-lane group emit their item's 8 logits
    if ((lane & 15) < 8) out[b * 8 + row] = osum;
}

extern "C" void kernel_launch(void* const* d_in, const int* in_sizes, int n_in,
                              void* d_out, int out_size, void* d_ws, size_t ws_size,
                              hipStream_t stream) {
    const float* S   = (const float*)d_in[0];
    const float* Wh  = (const float*)d_in[1];
    const float* bh  = (const float*)d_in[2];
    const float* Wr  = (const float*)d_in[3];
    const float* Wq  = (const float*)d_in[4];
    const float* w   = (const float*)d_in[5];
    const float* Wfc = (const float*)d_in[6];
    float* out = (float*)d_out;
    float* ws  = (float*)d_ws;

    const int B = in_sizes[0] / ROW;

    weff_kernel<<<1, 640, 0, stream>>>(Wh, bh, Wr, ws);

    // 4 waves/block, 4 items/wave => 16 items per block.
    const int grid = (B + 15) / 16;
    vin_kernel<<<grid, 256, 0, stream>>>(S, Wq, w, Wfc, ws, out, B);
}